// Round 10
// baseline (97.441 us; speedup 1.0000x reference)
//
#include <hip/hip_runtime.h>
#include <math.h>

#define NB 4
#define NN 512
#define DIN 128
#define DOUT 64
#define CHROWS 64
#define NCH (NN / CHROWS)

typedef __attribute__((ext_vector_type(8))) short short8;
typedef __attribute__((ext_vector_type(8))) unsigned short ushort8;
typedef __attribute__((ext_vector_type(4))) float f32x4;

__device__ __forceinline__ unsigned short f2bf(float f) {
    union { float f; unsigned u; } v; v.f = f;
    unsigned r = v.u + 0x7fffu + ((v.u >> 16) & 1u);  // round-nearest-even
    return (unsigned short)(r >> 16);
}

__device__ __forceinline__ float bf2f(unsigned short u) {
    union { unsigned u; float f; } v; v.u = ((unsigned)u) << 16; return v.f;
}

// Convert x (B*N*DIN f32) to bf16 in workspace.
__global__ void x_to_bf16(const float* __restrict__ x, unsigned short* __restrict__ xbf) {
    const int idx = blockIdx.x * 256 + threadIdx.x;   // 0..65535
    float4 v = ((const float4*)x)[idx];
    ushort4 o;
    o.x = f2bf(v.x); o.y = f2bf(v.y); o.z = f2bf(v.z); o.w = f2bf(v.w);
    ((ushort4*)xbf)[idx] = o;
}

__global__ __launch_bounds__(512, 4) void gat_main(
    const float* __restrict__ x,            // [B][N][128] f32
    const unsigned short* __restrict__ xbf, // [B][N][128] bf16
    const float* __restrict__ apw,   // [64][128]
    const float* __restrict__ apb,   // [64]
    const float* __restrict__ attw,  // [64]
    const float* __restrict__ pww,   // [64][128]
    const float* __restrict__ pwb,   // [64]
    const float* __restrict__ pow_,  // [64][128]
    const float* __restrict__ pob,   // [64]
    float* __restrict__ out)         // [B*N][64] pre-BN h
{
    __shared__ unsigned short xt[2][CHROWS * DIN];  // 2 x 16 KB double-buffered tile
    __shared__ float scp[2][NN];                    // 4 KB: per-o-half partial scores
    __shared__ float xis[DIN];                      // 512 B query row f32
    __shared__ float red_s[8];
    __shared__ float bcs1[1];

    // epilogue scratch aliased into xt (dead after score loop; 10.5 KB < 32 KB)
    float* pagg = (float*)&xt[0][0];              // [16][128] 8 KB
    float* aggs = pagg + 16 * DIN;                // [128]
    float* pr   = aggs + DIN;                     // [8][64] 2 KB

    const int t = threadIdx.x;
    const int blk = blockIdx.x;              // 0..2047: one query row (b, irow)
    const int b = blk >> 9;
    const int irow = blk & 511;
    const float* xb = x + (size_t)b * NN * DIN;
    const unsigned short* xbb = xbf + (size_t)b * NN * DIN;

    if (t < DIN) xis[t] = xb[(size_t)irow * DIN + t];

    const int lane = t & 63, wid = t >> 6;
    const int oh = wid & 1;          // o-half: o in [oh*32, oh*32+32)
    const int jq = wid >> 1;         // j-quarter: rows [jq*16, jq*16+16) of each chunk
    const int lr = lane & 15;
    const int g = lane >> 4;
    const int g8 = g * 8;

    // staging: 2 ushort8 (32 B) per thread per chunk, XOR-swizzled rows
    const int strow = t >> 3;
    const int sg = (t & 7) * 2;
    const int st_off0 = strow * 256 + (((sg + 0) ^ (strow & 7)) << 4);
    const int st_off1 = strow * 256 + (((sg + 1) ^ (strow & 7)) << 4);
    const int sgidx = strow * 16 + sg;

    const int rloc = jq * 16 + lr;
    int rdoff[4];
    #pragma unroll
    for (int ks = 0; ks < 4; ++ks)
        rdoff[ks] = rloc * 256 + ((((ks * 4 + g) ^ (rloc & 7))) << 4);

    // issue chunk-0 global loads early; A-prep hides the latency
    ushort8 v0 = ((const ushort8*)xbb)[sgidx];
    ushort8 v1 = ((const ushort8*)xbb)[sgidx + 1];

    __syncthreads();   // xis visible

    // A-fragments afr[ot][ks]: row o = oh*32 + ot*16 + lr, k = ks*32 + g8 + [0..8)
    short8 afr[2][4];
    #pragma unroll
    for (int ot = 0; ot < 2; ++ot) {
        const float* wrow = apw + (size_t)(oh * 32 + ot * 16 + lr) * DIN;
        #pragma unroll
        for (int ks = 0; ks < 4; ++ks) {
            float4 w0 = *(const float4*)(wrow + ks * 32 + g8);
            float4 w1 = *(const float4*)(wrow + ks * 32 + g8 + 4);
            const float* xk = xis + ks * 32 + g8;
            short8 fr;
            fr[0] = (short)f2bf(w0.x * xk[0]);
            fr[1] = (short)f2bf(w0.y * xk[1]);
            fr[2] = (short)f2bf(w0.z * xk[2]);
            fr[3] = (short)f2bf(w0.w * xk[3]);
            fr[4] = (short)f2bf(w1.x * xk[4]);
            fr[5] = (short)f2bf(w1.y * xk[5]);
            fr[6] = (short)f2bf(w1.z * xk[6]);
            fr[7] = (short)f2bf(w1.w * xk[7]);
            afr[ot][ks] = fr;
        }
    }

    // per-lane tanh constants for its 8 o's: o = oh*32 + ot*16 + g*4 + r
    // w*tanh(T) = w - 2w * rcp(exp2(T*C2) + 1),  C2 = 2*log2(e)
    const float C2 = 2.885390081777927f;
    float awm2[2][4], abc[2][4], sumw = 0.0f;
    #pragma unroll
    for (int ot = 0; ot < 2; ++ot)
        #pragma unroll
        for (int r = 0; r < 4; ++r) {
            const int o = oh * 32 + ot * 16 + g * 4 + r;
            float wv = attw[o], bv = apb[o];
            awm2[ot][r] = -2.0f * wv;
            abc[ot][r] = bv * C2;
            sumw += wv;
        }

    *(ushort8*)((char*)&xt[0][0] + st_off0) = v0;
    *(ushort8*)((char*)&xt[0][0] + st_off1) = v1;
    __syncthreads();   // xt[0] visible

    // T15 pipeline: MFMA(ch) overlaps post-processing of acc(ch-1)
    int p = 0;
    f32x4 accP0, accP1;
    #pragma unroll 2
    for (int ch = 0; ch < NCH; ++ch) {
        ushort8 vn0, vn1;
        if (ch + 1 < NCH) {
            vn0 = ((const ushort8*)xbb)[(ch + 1) * (CHROWS * DIN / 8) + sgidx];
            vn1 = ((const ushort8*)xbb)[(ch + 1) * (CHROWS * DIN / 8) + sgidx + 1];
        }

        short8 bfr[4];
        #pragma unroll
        for (int ks = 0; ks < 4; ++ks)
            bfr[ks] = *(const short8*)((const char*)&xt[p][0] + rdoff[ks]);

        f32x4 acc0 = {0.f, 0.f, 0.f, 0.f}, acc1 = {0.f, 0.f, 0.f, 0.f};
        #pragma unroll
        for (int ks = 0; ks < 4; ++ks)
            acc0 = __builtin_amdgcn_mfma_f32_16x16x32_bf16(afr[0][ks], bfr[ks], acc0, 0, 0, 0);
        #pragma unroll
        for (int ks = 0; ks < 4; ++ks)
            acc1 = __builtin_amdgcn_mfma_f32_16x16x32_bf16(afr[1][ks], bfr[ks], acc1, 0, 0, 0);

        // post-process PREVIOUS chunk while MFMA pipe drains
        if (ch > 0) {
            const int jp = (ch - 1) * CHROWS + jq * 16;
            float sp = sumw;
            #pragma unroll
            for (int r = 0; r < 4; ++r) {
                float arg = fmaf(accP0[r], C2, abc[0][r]);
                float u, rc;
                asm("v_exp_f32 %0, %1" : "=v"(u) : "v"(arg));
                float den = u + 1.0f;
                asm("v_rcp_f32 %0, %1" : "=v"(rc) : "v"(den));
                sp = fmaf(awm2[0][r], rc, sp);
            }
            #pragma unroll
            for (int r = 0; r < 4; ++r) {
                float arg = fmaf(accP1[r], C2, abc[1][r]);
                float u, rc;
                asm("v_exp_f32 %0, %1" : "=v"(u) : "v"(arg));
                float den = u + 1.0f;
                asm("v_rcp_f32 %0, %1" : "=v"(rc) : "v"(den));
                sp = fmaf(awm2[1][r], rc, sp);
            }
            sp += __shfl_xor(sp, 16);
            sp += __shfl_xor(sp, 32);
            if (lane < 16) scp[oh][jp + lane] = sp;
        }

        if (ch + 1 < NCH) {
            *(ushort8*)((char*)&xt[p ^ 1][0] + st_off0) = vn0;
            *(ushort8*)((char*)&xt[p ^ 1][0] + st_off1) = vn1;
        }
        __syncthreads();
        accP0 = acc0; accP1 = acc1;
        p ^= 1;
    }
    // final post for chunk NCH-1
    {
        const int jp = (NCH - 1) * CHROWS + jq * 16;
        float sp = sumw;
        #pragma unroll
        for (int r = 0; r < 4; ++r) {
            float arg = fmaf(accP0[r], C2, abc[0][r]);
            float u, rc;
            asm("v_exp_f32 %0, %1" : "=v"(u) : "v"(arg));
            float den = u + 1.0f;
            asm("v_rcp_f32 %0, %1" : "=v"(rc) : "v"(den));
            sp = fmaf(awm2[0][r], rc, sp);
        }
        #pragma unroll
        for (int r = 0; r < 4; ++r) {
            float arg = fmaf(accP1[r], C2, abc[1][r]);
            float u, rc;
            asm("v_exp_f32 %0, %1" : "=v"(u) : "v"(arg));
            float den = u + 1.0f;
            asm("v_rcp_f32 %0, %1" : "=v"(rc) : "v"(den));
            sp = fmaf(awm2[1][r], rc, sp);
        }
        sp += __shfl_xor(sp, 16);
        sp += __shfl_xor(sp, 32);
        if (lane < 16) scp[oh][jp + lane] = sp;
    }
    __syncthreads();

    // softmax over j (no max-subtraction: |score| <= sum|w| ~ 8, f32-safe)
    {
        float s = scp[0][t] + scp[1][t];
        float e = __expf(s);
        scp[0][t] = e;       // esc[j]; only thread t touches column t
        float ss = e;
        #pragma unroll
        for (int msk = 1; msk < 64; msk <<= 1) ss += __shfl_xor(ss, msk);
        if (lane == 0) red_s[wid] = ss;
    }
    __syncthreads();
    if (t == 0) {
        float sm = 0.f;
        #pragma unroll
        for (int w = 0; w < 8; ++w) sm += red_s[w];
        bcs1[0] = 1.0f / sm;
    }
    __syncthreads();

    // agg[d] = invs * sum_j e[j] * x[b,j,d]  — ushort4-vectorized
    const float* esc = &scp[0][0];
    {
        const int d0 = (t & 31) * 4, q = t >> 5;   // q in 0..15, 32 j each
        const unsigned short* xc = xbb + d0;
        float a0 = 0.f, a1 = 0.f, a2 = 0.f, a3 = 0.f;
        #pragma unroll 4
        for (int jj = q * 32; jj < q * 32 + 32; ++jj) {
            ushort4 xv = *(const ushort4*)(xc + (size_t)jj * DIN);
            float ev = esc[jj];
            a0 = fmaf(ev, bf2f(xv.x), a0);
            a1 = fmaf(ev, bf2f(xv.y), a1);
            a2 = fmaf(ev, bf2f(xv.z), a2);
            a3 = fmaf(ev, bf2f(xv.w), a3);
        }
        pagg[q * DIN + d0 + 0] = a0;
        pagg[q * DIN + d0 + 1] = a1;
        pagg[q * DIN + d0 + 2] = a2;
        pagg[q * DIN + d0 + 3] = a3;
    }
    __syncthreads();
    if (t < DIN) {
        float s = 0.f;
        #pragma unroll
        for (int q = 0; q < 16; ++q) s += pagg[q * DIN + t];
        aggs[t] = s * bcs1[0];
    }
    __syncthreads();

    // projections: o = t&63, pi = t>>6 (8 parts of 16 d each)
    {
        const int o = t & 63, pi = t >> 6;
        const float* w1 = pww + (size_t)o * DIN + pi * 16;
        const float* w2 = pow_ + (size_t)o * DIN + pi * 16;
        const float* ag = aggs + pi * 16;
        const float* xr = xis + pi * 16;
        float sum = 0.0f;
        #pragma unroll
        for (int dd = 0; dd < 16; ++dd)
            sum += w1[dd] * ag[dd] + w2[dd] * xr[dd];
        pr[pi * DOUT + o] = sum;
    }
    __syncthreads();
    if (t < DOUT) {
        float h = pwb[t] + pob[t];
        #pragma unroll
        for (int pi = 0; pi < 8; ++pi) h += pr[pi * DOUT + t];
        out[(size_t)blk * DOUT + t] = h;
    }
}

// Per-channel batch stats over (B*N, 64); deterministic tree reduction.
__global__ void bn_stats(const float* __restrict__ h, float* __restrict__ stats) {
    const int c = blockIdx.x;
    const int t = threadIdx.x;
    float s = 0.f, s2 = 0.f;
    for (int r = t; r < NB * NN; r += 256) {
        float v = h[(size_t)r * DOUT + c];
        s += v; s2 += v * v;
    }
    __shared__ float rs[256], rs2[256];
    rs[t] = s; rs2[t] = s2;
    __syncthreads();
    for (int k = 128; k > 0; k >>= 1) {
        if (t < k) { rs[t] += rs[t + k]; rs2[t] += rs2[t + k]; }
        __syncthreads();
    }
    if (t == 0) {
        const float inv_n = 1.0f / (float)(NB * NN);
        float mean = rs[0] * inv_n;
        float var = rs2[0] * inv_n - mean * mean;   // biased, as torch BN
        stats[c] = mean;
        stats[DOUT + c] = rsqrtf(var + 1e-5f);
    }
}

__global__ void bn_selu(float* __restrict__ out, const float* __restrict__ stats,
                        const float* __restrict__ gamma, const float* __restrict__ beta) {
    const int idx = blockIdx.x * 256 + threadIdx.x;
    const int c = idx & 63;
    float v = out[idx];
    float y = (v - stats[c]) * stats[DOUT + c] * gamma[c] + beta[c];
    const float scale = 1.0507009873554805f;
    const float alpha = 1.6732632423543772f;
    out[idx] = y > 0.0f ? scale * y : scale * alpha * (__expf(y) - 1.0f);
}

extern "C" void kernel_launch(void* const* d_in, const int* in_sizes, int n_in,
                              void* d_out, int out_size, void* d_ws, size_t ws_size,
                              hipStream_t stream) {
    const float* x    = (const float*)d_in[0];
    const float* apw  = (const float*)d_in[1];
    const float* apb  = (const float*)d_in[2];
    const float* attw = (const float*)d_in[3];
    const float* pww  = (const float*)d_in[4];
    const float* pwb  = (const float*)d_in[5];
    const float* pow_ = (const float*)d_in[6];
    const float* pob  = (const float*)d_in[7];
    const float* gmm  = (const float*)d_in[8];
    const float* bta  = (const float*)d_in[9];
    float* out = (float*)d_out;
    float* stats = (float*)d_ws;                                 // 128 floats
    unsigned short* xbf = (unsigned short*)((char*)d_ws + 1024); // 512 KB bf16 x

    x_to_bf16<<<256, 256, 0, stream>>>(x, xbf);
    gat_main<<<NB * NN, 512, 0, stream>>>(x, xbf, apw, apb, attw, pww, pwb, pow_, pob, out);
    bn_stats<<<DOUT, 256, 0, stream>>>(out, stats);
    bn_selu<<<(NB * NN * DOUT) / 256, 256, 0, stream>>>(out, stats, gmm, bta);
}

// Round 11
// 88.053 us; speedup vs baseline: 1.1066x; 1.1066x over previous
//
#include <hip/hip_runtime.h>
#include <math.h>

#define NB 4
#define NN 512
#define DIN 128
#define DOUT 64
#define TI 4
#define CHROWS 32
#define NCH (NN / CHROWS)   // 16

typedef __attribute__((ext_vector_type(8))) short short8;
typedef __attribute__((ext_vector_type(8))) unsigned short ushort8;
typedef __attribute__((ext_vector_type(4))) float f32x4;

__device__ __forceinline__ unsigned short f2bf(float f) {
    union { float f; unsigned u; } v; v.f = f;
    unsigned r = v.u + 0x7fffu + ((v.u >> 16) & 1u);  // round-nearest-even
    return (unsigned short)(r >> 16);
}

__device__ __forceinline__ float bf2f(unsigned short u) {
    union { unsigned u; float f; } v; v.u = ((unsigned)u) << 16; return v.f;
}

// Convert x (B*N*DIN f32) to bf16 in workspace.
__global__ void x_to_bf16(const float* __restrict__ x, unsigned short* __restrict__ xbf) {
    const int idx = blockIdx.x * 256 + threadIdx.x;   // 0..65535
    float4 v = ((const float4*)x)[idx];
    ushort4 o;
    o.x = f2bf(v.x); o.y = f2bf(v.y); o.z = f2bf(v.z); o.w = f2bf(v.w);
    ((ushort4*)xbf)[idx] = o;
}

__global__ __launch_bounds__(512, 4) void gat_main(
    const float* __restrict__ x,            // [B][N][128] f32
    const unsigned short* __restrict__ xbf, // [B][N][128] bf16
    const float* __restrict__ apw,   // [64][128]
    const float* __restrict__ apb,   // [64]
    const float* __restrict__ attw,  // [64]
    const float* __restrict__ pww,   // [64][128]
    const float* __restrict__ pwb,   // [64]
    const float* __restrict__ pow_,  // [64][128]
    const float* __restrict__ pob,   // [64]
    float* __restrict__ out)         // [B*N][64] pre-BN h
{
    __shared__ unsigned short xt[2][CHROWS * DIN];  // 16 KB dbuf tiles
    __shared__ float scp[4][NN][TI];                // 32 KB [og][j][i] partial scores
    __shared__ float xis[TI][DIN];                  // 2 KB query rows f32
    __shared__ float red_s[8][TI];
    __shared__ float bcs[TI];

    // epilogue aliases
    float* pagg = (float*)&xt[0][0];                // [8][TI][DIN] = 16 KB (== xt)
    float* aggs = &scp[1][0][0];                    // [TI][DIN] 2 KB (scp[1..3] dead then)
    float* pr   = aggs + TI * DIN;                  // [8][DOUT] 2 KB

    const int t = threadIdx.x;
    const int blk = blockIdx.x;              // 0..511
    const int b = blk >> 7;
    const int rowbase = (blk & 127) * TI;
    const float* xb = x + (size_t)b * NN * DIN;
    const unsigned short* xbb = xbf + (size_t)b * NN * DIN;

    {
        const int i = t >> 7, d = t & 127;
        xis[i][d] = xb[(size_t)(rowbase + i) * DIN + d];
    }

    const int lane = t & 63, wid = t >> 6;
    const int og = wid & 3;          // o in [og*16, og*16+16)
    const int jsub = wid >> 2;       // j-rows [jsub*16, jsub*16+16) of each chunk
    const int lr = lane & 15;
    const int g = lane >> 4;
    const int g8 = g * 8;

    // staging: one ushort8 (16 B) per thread per chunk, XOR-swizzled granules
    const int strow = t >> 4, stgr = t & 15;
    const int st_off = strow * 256 + ((stgr ^ (strow & 7)) << 4);
    const int rloc = jsub * 16 + lr;
    int rdoff[4];
    #pragma unroll
    for (int ks = 0; ks < 4; ++ks)
        rdoff[ks] = rloc * 256 + (((ks * 4 + g) ^ (rloc & 7)) << 4);

    // issue chunk-0 load early; xis barrier + A-prep hide its latency
    ushort8 v0 = ((const ushort8*)xbb)[t];
    __syncthreads();   // xis visible

    // A-fragments afr[i][ks]: row o = og*16+lr, k = ks*32+g8+[0..8)
    short8 afr[TI][4];
    {
        const float* wrow = apw + (size_t)(og * 16 + lr) * DIN;
        #pragma unroll
        for (int ks = 0; ks < 4; ++ks) {
            float4 w0 = *(const float4*)(wrow + ks * 32 + g8);
            float4 w1 = *(const float4*)(wrow + ks * 32 + g8 + 4);
            #pragma unroll
            for (int i = 0; i < TI; ++i) {
                const float* xk = &xis[i][ks * 32 + g8];
                short8 fr;
                fr[0] = (short)f2bf(w0.x * xk[0]);
                fr[1] = (short)f2bf(w0.y * xk[1]);
                fr[2] = (short)f2bf(w0.z * xk[2]);
                fr[3] = (short)f2bf(w0.w * xk[3]);
                fr[4] = (short)f2bf(w1.x * xk[4]);
                fr[5] = (short)f2bf(w1.y * xk[5]);
                fr[6] = (short)f2bf(w1.z * xk[6]);
                fr[7] = (short)f2bf(w1.w * xk[7]);
                afr[i][ks] = fr;
            }
        }
    }

    // per-lane tanh constants for its 4 o's: o = og*16 + g*4 + r
    // w*tanh(T) = w - 2w*rcp(exp2(T*C2)+1),  C2 = 2*log2(e)
    const float C2 = 2.885390081777927f;
    float awm2[4], abc[4], sumw = 0.0f;
    #pragma unroll
    for (int r = 0; r < 4; ++r) {
        const int o = og * 16 + g * 4 + r;
        float wv = attw[o], bv = apb[o];
        awm2[r] = -2.0f * wv;
        abc[r] = bv * C2;
        sumw += wv;
    }

    *(ushort8*)((char*)&xt[0][0] + st_off) = v0;
    __syncthreads();   // xt[0] visible

    f32x4 accA[TI], accB[TI];

    auto COMPUTE = [&](f32x4 (&acc)[TI], const int buf) {
        #pragma unroll
        for (int i = 0; i < TI; ++i) acc[i] = f32x4{0.f, 0.f, 0.f, 0.f};
        #pragma unroll
        for (int ks = 0; ks < 4; ++ks) {
            short8 bk = *(const short8*)((const char*)&xt[buf][0] + rdoff[ks]);
            #pragma unroll
            for (int i = 0; i < TI; ++i)
                acc[i] = __builtin_amdgcn_mfma_f32_16x16x32_bf16(afr[i][ks], bk, acc[i], 0, 0, 0);
        }
    };

    auto POST = [&](f32x4 (&acc)[TI], const int ch) {
        const int jp = ch * CHROWS + jsub * 16;
        float sp[TI];
        #pragma unroll
        for (int i = 0; i < TI; ++i) {
            float s = sumw;
            #pragma unroll
            for (int r = 0; r < 4; ++r) {
                float arg = fmaf(acc[i][r], C2, abc[r]);
                float u, rc;
                asm("v_exp_f32 %0, %1" : "=v"(u) : "v"(arg));
                float den = u + 1.0f;
                asm("v_rcp_f32 %0, %1" : "=v"(rc) : "v"(den));
                s = fmaf(awm2[r], rc, s);
            }
            sp[i] = s;
        }
        #pragma unroll
        for (int i = 0; i < TI; ++i) sp[i] += __shfl_xor(sp[i], 16);
        #pragma unroll
        for (int i = 0; i < TI; ++i) sp[i] += __shfl_xor(sp[i], 32);
        if (lane < 16) {
            f32x4 v = {sp[0], sp[1], sp[2], sp[3]};
            *(f32x4*)&scp[og][jp + lane][0] = v;   // one ds_write_b128
        }
    };

    // chunk 0
    {
        ushort8 vn = ((const ushort8*)xbb)[1 * 512 + t];
        COMPUTE(accA, 0);
        *(ushort8*)((char*)&xt[1][0] + st_off) = vn;
        __syncthreads();
    }
    // chunks 1..14 (2 per iteration, static buffer parity, no acc copies)
    for (int cb = 1; cb <= NCH - 3; cb += 2) {
        {
            ushort8 vn = ((const ushort8*)xbb)[(cb + 1) * 512 + t];
            COMPUTE(accB, 1);          // chunk cb (odd)
            POST(accA, cb - 1);
            *(ushort8*)((char*)&xt[0][0] + st_off) = vn;
            __syncthreads();
        }
        {
            ushort8 vn = ((const ushort8*)xbb)[(cb + 2) * 512 + t];
            COMPUTE(accA, 0);          // chunk cb+1 (even)
            POST(accB, cb);
            *(ushort8*)((char*)&xt[1][0] + st_off) = vn;
            __syncthreads();
        }
    }
    // chunk 15
    COMPUTE(accB, 1);
    POST(accA, NCH - 2);
    POST(accB, NCH - 1);
    __syncthreads();

    // softmax over j (no max-subtraction: |score| <= sum|w| ~ 8, f32-safe)
    {
        f32x4 s4 = *(const f32x4*)&scp[0][t][0];
        s4 += *(const f32x4*)&scp[1][t][0];
        s4 += *(const f32x4*)&scp[2][t][0];
        s4 += *(const f32x4*)&scp[3][t][0];
        float e0 = __expf(s4[0]), e1 = __expf(s4[1]), e2 = __expf(s4[2]), e3 = __expf(s4[3]);
        f32x4 ev = {e0, e1, e2, e3};
        *(f32x4*)&scp[0][t][0] = ev;   // thread t owns column t
        float ss[TI] = {e0, e1, e2, e3};
        #pragma unroll
        for (int msk = 1; msk < 64; msk <<= 1)
            #pragma unroll
            for (int i = 0; i < TI; ++i) ss[i] += __shfl_xor(ss[i], msk);
        if (lane == 0)
            #pragma unroll
            for (int i = 0; i < TI; ++i) red_s[wid][i] = ss[i];
    }
    __syncthreads();
    if (t < TI) {
        float sm = 0.f;
        #pragma unroll
        for (int w = 0; w < 8; ++w) sm += red_s[w][t];
        bcs[t] = 1.0f / sm;
    }
    __syncthreads();

    // agg[i][d] = invs_i * sum_j e[i][j] * x[b,j,d]
    {
        const int d0 = (t & 63) * 2, q = t >> 6;   // 8 quarters of 64 j
        const unsigned short* xc = xbb + d0;
        float a0[TI] = {0.f, 0.f, 0.f, 0.f};
        float a1[TI] = {0.f, 0.f, 0.f, 0.f};
        for (int jj = q * 64; jj < q * 64 + 64; ++jj) {
            ushort2 xv = *(const ushort2*)(xc + (size_t)jj * DIN);
            float x0 = bf2f(xv.x), x1 = bf2f(xv.y);
            const f32x4 ev = *(const f32x4*)&scp[0][jj][0];
            #pragma unroll
            for (int i = 0; i < TI; ++i) {
                a0[i] = fmaf(ev[i], x0, a0[i]);
                a1[i] = fmaf(ev[i], x1, a1[i]);
            }
        }
        #pragma unroll
        for (int i = 0; i < TI; ++i) {
            pagg[(q * TI + i) * DIN + d0] = a0[i];
            pagg[(q * TI + i) * DIN + d0 + 1] = a1[i];
        }
    }
    __syncthreads();
    {
        const int i = t >> 7, d = t & 127;
        float s = 0.f;
        #pragma unroll
        for (int q = 0; q < 8; ++q) s += pagg[(q * TI + i) * DIN + d];
        aggs[i * DIN + d] = s * bcs[i];
    }
    __syncthreads();

    // projections: pi = t>>6 -> i = pi>>1, d-half = pi&1 (64 d each)
    {
        const int o = t & 63, pi = t >> 6;
        const int i = pi >> 1, part = pi & 1;
        const float* w1 = pww + (size_t)o * DIN + part * 64;
        const float* w2 = pow_ + (size_t)o * DIN + part * 64;
        const float* ag = aggs + i * DIN + part * 64;
        const float* xr = &xis[i][part * 64];
        float sum = 0.0f;
        #pragma unroll
        for (int dd = 0; dd < 64; ++dd)
            sum += w1[dd] * ag[dd] + w2[dd] * xr[dd];
        pr[pi * DOUT + o] = sum;
    }
    __syncthreads();
    if (t < TI * DOUT) {
        const int i = t >> 6, o = t & 63;
        float h = pr[(i * 2) * DOUT + o] + pr[(i * 2 + 1) * DOUT + o] + pwb[o] + pob[o];
        out[(size_t)(b * NN + rowbase + i) * DOUT + o] = h;
    }
}

// Per-channel batch stats over (B*N, 64); deterministic tree reduction.
__global__ void bn_stats(const float* __restrict__ h, float* __restrict__ stats) {
    const int c = blockIdx.x;
    const int t = threadIdx.x;
    float s = 0.f, s2 = 0.f;
    for (int r = t; r < NB * NN; r += 256) {
        float v = h[(size_t)r * DOUT + c];
        s += v; s2 += v * v;
    }
    __shared__ float rs[256], rs2[256];
    rs[t] = s; rs2[t] = s2;
    __syncthreads();
    for (int k = 128; k > 0; k >>= 1) {
        if (t < k) { rs[t] += rs[t + k]; rs2[t] += rs2[t + k]; }
        __syncthreads();
    }
    if (t == 0) {
        const float inv_n = 1.0f / (float)(NB * NN);
        float mean = rs[0] * inv_n;
        float var = rs2[0] * inv_n - mean * mean;   // biased, as torch BN
        stats[c] = mean;
        stats[DOUT + c] = rsqrtf(var + 1e-5f);
    }
}

__global__ void bn_selu(float* __restrict__ out, const float* __restrict__ stats,
                        const float* __restrict__ gamma, const float* __restrict__ beta) {
    const int idx = blockIdx.x * 256 + threadIdx.x;
    const int c = idx & 63;
    float v = out[idx];
    float y = (v - stats[c]) * stats[DOUT + c] * gamma[c] + beta[c];
    const float scale = 1.0507009873554805f;
    const float alpha = 1.6732632423543772f;
    out[idx] = y > 0.0f ? scale * y : scale * alpha * (__expf(y) - 1.0f);
}

extern "C" void kernel_launch(void* const* d_in, const int* in_sizes, int n_in,
                              void* d_out, int out_size, void* d_ws, size_t ws_size,
                              hipStream_t stream) {
    const float* x    = (const float*)d_in[0];
    const float* apw  = (const float*)d_in[1];
    const float* apb  = (const float*)d_in[2];
    const float* attw = (const float*)d_in[3];
    const float* pww  = (const float*)d_in[4];
    const float* pwb  = (const float*)d_in[5];
    const float* pow_ = (const float*)d_in[6];
    const float* pob  = (const float*)d_in[7];
    const float* gmm  = (const float*)d_in[8];
    const float* bta  = (const float*)d_in[9];
    float* out = (float*)d_out;
    float* stats = (float*)d_ws;                                 // 128 floats
    unsigned short* xbf = (unsigned short*)((char*)d_ws + 1024); // 512 KB bf16 x

    x_to_bf16<<<256, 256, 0, stream>>>(x, xbf);
    gat_main<<<NB * NN / TI, 512, 0, stream>>>(x, xbf, apw, apb, attw, pww, pwb, pow_, pob, out);
    bn_stats<<<DOUT, 256, 0, stream>>>(out, stats);
    bn_selu<<<(NB * NN * DOUT) / 256, 256, 0, stream>>>(out, stats, gmm, bta);
}

// Round 12
// 66.736 us; speedup vs baseline: 1.4601x; 1.3194x over previous
//
#include <hip/hip_runtime.h>
#include <math.h>

#define NB 4
#define NN 512
#define DIN 128
#define DOUT 64
#define TI 2
#define CHROWS 32
#define NCH (NN / CHROWS)   // 16

typedef __attribute__((ext_vector_type(8))) short short8;
typedef __attribute__((ext_vector_type(8))) unsigned short ushort8;
typedef __attribute__((ext_vector_type(16))) float f32x16;

__device__ __forceinline__ unsigned short f2bf(float f) {
    union { float f; unsigned u; } v; v.f = f;
    unsigned r = v.u + 0x7fffu + ((v.u >> 16) & 1u);  // round-nearest-even
    return (unsigned short)(r >> 16);
}

__device__ __forceinline__ float bf2f(unsigned short u) {
    union { unsigned u; float f; } v; v.u = ((unsigned)u) << 16; return v.f;
}

// Convert x (B*N*DIN f32) to bf16 in workspace.
__global__ void x_to_bf16(const float* __restrict__ x, unsigned short* __restrict__ xbf) {
    const int idx = blockIdx.x * 256 + threadIdx.x;   // 0..65535
    float4 v = ((const float4*)x)[idx];
    ushort4 o;
    o.x = f2bf(v.x); o.y = f2bf(v.y); o.z = f2bf(v.z); o.w = f2bf(v.w);
    ((ushort4*)xbf)[idx] = o;
}

__global__ __launch_bounds__(256, 3) void gat_main(
    const float* __restrict__ x,            // [B][N][128] f32
    const unsigned short* __restrict__ xbf, // [B][N][128] bf16
    const float* __restrict__ apw,   // [64][128]
    const float* __restrict__ apb,   // [64]
    const float* __restrict__ attw,  // [64]
    const float* __restrict__ pww,   // [64][128]
    const float* __restrict__ pwb,   // [64]
    const float* __restrict__ pow_,  // [64][128]
    const float* __restrict__ pob,   // [64]
    float* __restrict__ out)         // [B*N][64] pre-BN h
{
    __shared__ unsigned short xt[2][CHROWS * DIN];  // 16 KB dbuf tiles
    __shared__ float scp[2][TI][NN];                // 8 KB [oh][i][j] partial scores
    __shared__ float xis[TI][DIN];                  // 1 KB query rows f32
    __shared__ float red_s[4][TI];
    __shared__ float bcs[TI];

    // epilogue aliases into xt (dead after score loop; 10 KB <= 16 KB)
    float* pagg = (float*)&xt[0][0];                // [8][TI][DIN] 8 KB
    float* aggs = pagg + 8 * TI * DIN;              // [TI][DIN] 1 KB
    float* pr   = aggs + TI * DIN;                  // [4][DOUT] 1 KB

    const int t = threadIdx.x;
    const int blk = blockIdx.x;              // 0..1023
    const int b = blk >> 8;
    const int rowbase = (blk & 255) * TI;
    const float* xb = x + (size_t)b * NN * DIN;
    const unsigned short* xbb = xbf + (size_t)b * NN * DIN;

    {
        const int i = t >> 7, d = t & 127;
        xis[i][d] = xb[(size_t)(rowbase + i) * DIN + d];
    }

    const int lane = t & 63, wid = t >> 6;   // 4 waves
    const int qi = wid & 1;                  // query-row index this wave serves
    const int oh = wid >> 1;                 // o-half: o in [oh*32, oh*32+32)
    const int l31 = lane & 31;
    const int hi = lane >> 5;

    // staging: 2 ushort8 (32 B) per thread per chunk, granule-XOR swizzle
    const int r0 = t >> 4, g0 = t & 15;
    const int st_off0 = r0 * 256 + ((g0 ^ (r0 & 7)) << 4);
    const int r1 = 16 + r0;
    const int st_off1 = r1 * 256 + ((g0 ^ (r1 & 7)) << 4);

    // read offsets: row = l31, logical granule = ks*2 + hi
    int rdoff[8];
    #pragma unroll
    for (int ks = 0; ks < 8; ++ks)
        rdoff[ks] = l31 * 256 + (((ks * 2 + hi) ^ (l31 & 7)) << 4);

    // issue chunk-0 loads early; xis barrier + A-prep hide the latency
    ushort8 v0a = ((const ushort8*)xbb)[t];
    ushort8 v0b = ((const ushort8*)xbb)[t + 256];
    __syncthreads();   // xis visible

    // A fragments afr[ks]: row o = oh*32 + l31, k = ks*16 + hi*8 + [0..8)
    short8 afr[8];
    {
        const float* wrow = apw + (size_t)(oh * 32 + l31) * DIN;
        const float* xk0 = &xis[qi][0];
        #pragma unroll
        for (int ks = 0; ks < 8; ++ks) {
            const int k0 = ks * 16 + hi * 8;
            float4 w0 = *(const float4*)(wrow + k0);
            float4 w1 = *(const float4*)(wrow + k0 + 4);
            const float* xk = xk0 + k0;
            short8 fr;
            fr[0] = (short)f2bf(w0.x * xk[0]);
            fr[1] = (short)f2bf(w0.y * xk[1]);
            fr[2] = (short)f2bf(w0.z * xk[2]);
            fr[3] = (short)f2bf(w0.w * xk[3]);
            fr[4] = (short)f2bf(w1.x * xk[4]);
            fr[5] = (short)f2bf(w1.y * xk[5]);
            fr[6] = (short)f2bf(w1.z * xk[6]);
            fr[7] = (short)f2bf(w1.w * xk[7]);
            afr[ks] = fr;
        }
    }

    // per-lane tanh constants for the 16 o's this lane's acc rows cover:
    // crow(r) = (r&3) + 8*(r>>2) + 4*hi  (verified C/D layout m74/m101)
    // w*tanh(T) = w - 2w*rcp(exp2(T*C2)+1), C2 = 2*log2(e)
    const float C2 = 2.885390081777927f;
    float awm2[16], abc[16], sumw = 0.0f;
    #pragma unroll
    for (int r = 0; r < 16; ++r) {
        const int crow = (r & 3) + 8 * (r >> 2) + 4 * hi;
        const int o = oh * 32 + crow;
        float wv = attw[o], bv = apb[o];
        awm2[r] = -2.0f * wv;
        abc[r] = bv * C2;
        sumw += wv;
    }

    *(ushort8*)((char*)&xt[0][0] + st_off0) = v0a;
    *(ushort8*)((char*)&xt[0][0] + st_off1) = v0b;
    __syncthreads();   // xt[0] visible

    f32x16 accA, accB;

#define COMPUTE(ACC, BUF) do {                                                  \
    f32x16 zz_ = {0.f,0.f,0.f,0.f,0.f,0.f,0.f,0.f,                              \
                  0.f,0.f,0.f,0.f,0.f,0.f,0.f,0.f};                             \
    ACC = zz_;                                                                  \
    _Pragma("unroll")                                                           \
    for (int ks_ = 0; ks_ < 8; ++ks_) {                                         \
        short8 bk_ = *(const short8*)((const char*)&xt[BUF][0] + rdoff[ks_]);   \
        ACC = __builtin_amdgcn_mfma_f32_32x32x16_bf16(afr[ks_], bk_, ACC, 0, 0, 0); \
    }                                                                           \
} while (0)

#define POST(ACC, CH) do {                                                      \
    float sp_ = sumw;                                                           \
    _Pragma("unroll")                                                           \
    for (int r_ = 0; r_ < 16; ++r_) {                                           \
        float arg_ = fmaf(ACC[r_], C2, abc[r_]);                                \
        float u_, rc_;                                                          \
        asm("v_exp_f32 %0, %1" : "=v"(u_) : "v"(arg_));                         \
        float den_ = u_ + 1.0f;                                                 \
        asm("v_rcp_f32 %0, %1" : "=v"(rc_) : "v"(den_));                        \
        sp_ = fmaf(awm2[r_], rc_, sp_);                                         \
    }                                                                           \
    sp_ += __shfl_xor(sp_, 32);                                                 \
    if (lane < 32) scp[oh][qi][(CH) * 32 + l31] = sp_;                          \
} while (0)

    // chunk 0
    {
        ushort8 va = ((const ushort8*)xbb)[512 + t];
        ushort8 vb = ((const ushort8*)xbb)[512 + t + 256];
        COMPUTE(accA, 0);
        *(ushort8*)((char*)&xt[1][0] + st_off0) = va;
        *(ushort8*)((char*)&xt[1][0] + st_off1) = vb;
        __syncthreads();
    }
    // chunks 1..14, two per iteration, static buffer parity
    for (int cb = 1; cb <= NCH - 3; cb += 2) {
        {
            ushort8 va = ((const ushort8*)xbb)[(cb + 1) * 512 + t];
            ushort8 vb = ((const ushort8*)xbb)[(cb + 1) * 512 + t + 256];
            COMPUTE(accB, 1);           // chunk cb (odd)
            POST(accA, cb - 1);
            *(ushort8*)((char*)&xt[0][0] + st_off0) = va;
            *(ushort8*)((char*)&xt[0][0] + st_off1) = vb;
            __syncthreads();
        }
        {
            ushort8 va = ((const ushort8*)xbb)[(cb + 2) * 512 + t];
            ushort8 vb = ((const ushort8*)xbb)[(cb + 2) * 512 + t + 256];
            COMPUTE(accA, 0);           // chunk cb+1 (even)
            POST(accB, cb);
            *(ushort8*)((char*)&xt[1][0] + st_off0) = va;
            *(ushort8*)((char*)&xt[1][0] + st_off1) = vb;
            __syncthreads();
        }
    }
    // chunk 15
    COMPUTE(accB, 1);
    POST(accA, NCH - 2);
    POST(accB, NCH - 1);
    __syncthreads();

    // softmax over j (no max-subtraction: |score| <= sum|w| ~ 8, f32-safe)
    {
        float s00 = scp[0][0][t] + scp[1][0][t];
        float s01 = scp[0][0][t + 256] + scp[1][0][t + 256];
        float s10 = scp[0][1][t] + scp[1][1][t];
        float s11 = scp[0][1][t + 256] + scp[1][1][t + 256];
        float e00 = __expf(s00), e01 = __expf(s01);
        float e10 = __expf(s10), e11 = __expf(s11);
        scp[0][0][t] = e00; scp[0][0][t + 256] = e01;   // esc[0][j]
        scp[0][1][t] = e10; scp[0][1][t + 256] = e11;   // esc[1][j]
        float ss0 = e00 + e01, ss1 = e10 + e11;
        #pragma unroll
        for (int m = 1; m < 64; m <<= 1) {
            ss0 += __shfl_xor(ss0, m);
            ss1 += __shfl_xor(ss1, m);
        }
        if (lane == 0) { red_s[wid][0] = ss0; red_s[wid][1] = ss1; }
    }
    __syncthreads();
    if (t < TI) {
        float sm = red_s[0][t] + red_s[1][t] + red_s[2][t] + red_s[3][t];
        bcs[t] = 1.0f / sm;
    }
    __syncthreads();

    // agg[i][d] = invs_i * sum_j e[i][j] * x[b,j,d]  — ushort4-vectorized
    const float* esc0 = &scp[0][0][0];
    const float* esc1 = &scp[0][1][0];
    {
        const int d0 = (t & 31) * 4, q = t >> 5;   // 8 groups of 64 j
        const unsigned short* xc = xbb + d0;
        float a0[4] = {0.f, 0.f, 0.f, 0.f};
        float a1[4] = {0.f, 0.f, 0.f, 0.f};
        #pragma unroll 4
        for (int jj = q * 64; jj < q * 64 + 64; ++jj) {
            ushort4 xv = *(const ushort4*)(xc + (size_t)jj * DIN);
            float e0v = esc0[jj], e1v = esc1[jj];
            float x0 = bf2f(xv.x), x1 = bf2f(xv.y);
            float x2 = bf2f(xv.z), x3 = bf2f(xv.w);
            a0[0] = fmaf(e0v, x0, a0[0]); a0[1] = fmaf(e0v, x1, a0[1]);
            a0[2] = fmaf(e0v, x2, a0[2]); a0[3] = fmaf(e0v, x3, a0[3]);
            a1[0] = fmaf(e1v, x0, a1[0]); a1[1] = fmaf(e1v, x1, a1[1]);
            a1[2] = fmaf(e1v, x2, a1[2]); a1[3] = fmaf(e1v, x3, a1[3]);
        }
        #pragma unroll
        for (int c = 0; c < 4; ++c) {
            pagg[(q * TI + 0) * DIN + d0 + c] = a0[c];
            pagg[(q * TI + 1) * DIN + d0 + c] = a1[c];
        }
    }
    __syncthreads();
    {
        const int i = t >> 7, d = t & 127;
        float s = 0.f;
        #pragma unroll
        for (int q = 0; q < 8; ++q) s += pagg[(q * TI + i) * DIN + d];
        aggs[i * DIN + d] = s * bcs[i];
    }
    __syncthreads();

    // projections: pi = t>>6 in 0..3 -> i = pi>>1, d-half = pi&1 (64 d each)
    {
        const int o = t & 63, pi = t >> 6;
        const int i = pi >> 1, part = pi & 1;
        const float* w1 = pww + (size_t)o * DIN + part * 64;
        const float* w2 = pow_ + (size_t)o * DIN + part * 64;
        const float* ag = aggs + i * DIN + part * 64;
        const float* xr = &xis[i][part * 64];
        float sum = 0.0f;
        #pragma unroll
        for (int dd = 0; dd < 64; ++dd)
            sum += w1[dd] * ag[dd] + w2[dd] * xr[dd];
        pr[pi * DOUT + o] = sum;
    }
    __syncthreads();
    if (t < TI * DOUT) {
        const int i = t >> 6, o = t & 63;
        float h = pr[(i * 2) * DOUT + o] + pr[(i * 2 + 1) * DOUT + o] + pwb[o] + pob[o];
        out[(size_t)(b * NN + rowbase + i) * DOUT + o] = h;
    }
#undef COMPUTE
#undef POST
}

// Per-channel batch stats over (B*N, 64); deterministic tree reduction.
__global__ void bn_stats(const float* __restrict__ h, float* __restrict__ stats) {
    const int c = blockIdx.x;
    const int t = threadIdx.x;
    float s = 0.f, s2 = 0.f;
    for (int r = t; r < NB * NN; r += 256) {
        float v = h[(size_t)r * DOUT + c];
        s += v; s2 += v * v;
    }
    __shared__ float rs[256], rs2[256];
    rs[t] = s; rs2[t] = s2;
    __syncthreads();
    for (int k = 128; k > 0; k >>= 1) {
        if (t < k) { rs[t] += rs[t + k]; rs2[t] += rs2[t + k]; }
        __syncthreads();
    }
    if (t == 0) {
        const float inv_n = 1.0f / (float)(NB * NN);
        float mean = rs[0] * inv_n;
        float var = rs2[0] * inv_n - mean * mean;   // biased, as torch BN
        stats[c] = mean;
        stats[DOUT + c] = rsqrtf(var + 1e-5f);
    }
}

__global__ void bn_selu(float* __restrict__ out, const float* __restrict__ stats,
                        const float* __restrict__ gamma, const float* __restrict__ beta) {
    const int idx = blockIdx.x * 256 + threadIdx.x;
    const int c = idx & 63;
    float v = out[idx];
    float y = (v - stats[c]) * stats[DOUT + c] * gamma[c] + beta[c];
    const float scale = 1.0507009873554805f;
    const float alpha = 1.6732632423543772f;
    out[idx] = y > 0.0f ? scale * y : scale * alpha * (__expf(y) - 1.0f);
}

extern "C" void kernel_launch(void* const* d_in, const int* in_sizes, int n_in,
                              void* d_out, int out_size, void* d_ws, size_t ws_size,
                              hipStream_t stream) {
    const float* x    = (const float*)d_in[0];
    const float* apw  = (const float*)d_in[1];
    const float* apb  = (const float*)d_in[2];
    const float* attw = (const float*)d_in[3];
    const float* pww  = (const float*)d_in[4];
    const float* pwb  = (const float*)d_in[5];
    const float* pow_ = (const float*)d_in[6];
    const float* pob  = (const float*)d_in[7];
    const float* gmm  = (const float*)d_in[8];
    const float* bta  = (const float*)d_in[9];
    float* out = (float*)d_out;
    float* stats = (float*)d_ws;                                 // 128 floats
    unsigned short* xbf = (unsigned short*)((char*)d_ws + 1024); // 512 KB bf16 x

    x_to_bf16<<<256, 256, 0, stream>>>(x, xbf);
    gat_main<<<NB * NN / TI, 256, 0, stream>>>(x, xbf, apw, apb, attw, pww, pwb, pow_, pob, out);
    bn_stats<<<DOUT, 256, 0, stream>>>(out, stats);
    bn_selu<<<(NB * NN * DOUT) / 256, 256, 0, stream>>>(out, stats, gmm, bta);
}